// Round 1
// baseline (95.306 us; speedup 1.0000x reference)
//
#include <hip/hip_runtime.h>
#include <hip/hip_bf16.h>

#define H 1024
#define E 1024
#define VOCAB 50257
#define M 16384

__device__ __forceinline__ float sigmoidf_(float x) { return 1.0f / (1.0f + expf(-x)); }

__device__ __forceinline__ float wave_reduce_sum(float v) {
    #pragma unroll
    for (int o = 32; o > 0; o >>= 1) v += __shfl_down(v, o);
    return v;
}

// K1: gates + h.  grid 1024 blocks (one per hidden unit j), 256 thr (4 waves: i,f,g,o)
__global__ void k_lstm(const int* x, const float* emb, const float* W_ih, const float* W_hh,
                       const float* b_ih, const float* b_hh, const float* h0, const float* c0,
                       float* h_out) {
    int j = blockIdx.x;
    int w = threadIdx.x >> 6;
    int lane = threadIdx.x & 63;
    int r = w * H + j;                      // gate row: i=j, f=H+j, g=2H+j, o=3H+j
    const float4* A  = (const float4*)(W_ih + (size_t)r * E);
    const float4* Bm = (const float4*)(W_hh + (size_t)r * H);
    const float4* xe = (const float4*)(emb + (size_t)x[0] * E);
    const float4* hp = (const float4*)h0;
    float acc = 0.f;
    #pragma unroll
    for (int i = 0; i < 4; i++) {
        int idx = lane + 64 * i;
        float4 a = A[idx],  xv = xe[idx];
        acc += a.x * xv.x + a.y * xv.y + a.z * xv.z + a.w * xv.w;
        float4 b = Bm[idx], hv = hp[idx];
        acc += b.x * hv.x + b.y * hv.y + b.z * hv.z + b.w * hv.w;
    }
    acc = wave_reduce_sum(acc);
    __shared__ float g[4];
    if (lane == 0) g[w] = acc + b_ih[r] + b_hh[r];
    __syncthreads();
    if (threadIdx.x == 0) {
        float gi = g[0], gf = g[1], gg = g[2], go = g[3];
        float c = sigmoidf_(gf) * c0[j] + sigmoidf_(gi) * tanhf(gg);
        h_out[j] = sigmoidf_(go) * tanhf(c);
    }
}

// K2: v[k] = sum_j h[j] * Ws_w[j][k]   grid 64 blocks x 1024 thr, atomic accumulate
__global__ void k_hWs(const float* __restrict__ h, const float* __restrict__ Ws_w,
                      float* __restrict__ v) {
    int k = threadIdx.x;
    int j0 = blockIdx.x * 16;
    __shared__ float hs[16];
    if (threadIdx.x < 16) hs[threadIdx.x] = h[j0 + threadIdx.x];
    __syncthreads();
    float acc = 0.f;
    #pragma unroll
    for (int jj = 0; jj < 16; jj++)
        acc += hs[jj] * Ws_w[(size_t)(j0 + jj) * H + k];
    atomicAdd(&v[k], acc);
}

// K3: scores[m] = h_e_m[m] . v    grid 4096 x 256 (wave per m)
__global__ void k_scores(const float* __restrict__ hem, const float* __restrict__ v,
                         float* __restrict__ sc) {
    int m = blockIdx.x * 4 + (threadIdx.x >> 6);
    int lane = threadIdx.x & 63;
    const float4* A = (const float4*)(hem + (size_t)m * H);
    const float4* V4 = (const float4*)v;
    float acc = 0.f;
    #pragma unroll
    for (int i = 0; i < 4; i++) {
        int idx = lane + 64 * i;
        float4 a = A[idx], b = V4[idx];
        acc += a.x * b.x + a.y * b.y + a.z * b.z + a.w * b.w;
    }
    acc = wave_reduce_sum(acc);
    if (lane == 0) sc[m] = acc;
}

// K4: softmax over 16384 scores -> p_v (written to d_out region). 1 block x 1024 thr.
__global__ void k_softmax(const float* __restrict__ sc, float* __restrict__ pv) {
    int t = threadIdx.x;
    float vals[16];
    float lmax = -1e30f;
    #pragma unroll
    for (int i = 0; i < 16; i++) { vals[i] = sc[t + 1024 * i]; lmax = fmaxf(lmax, vals[i]); }
    __shared__ float s[1024];
    s[t] = lmax; __syncthreads();
    for (int o = 512; o > 0; o >>= 1) { if (t < o) s[t] = fmaxf(s[t], s[t + o]); __syncthreads(); }
    float gmax = s[0];
    __syncthreads();
    float lsum = 0.f;
    #pragma unroll
    for (int i = 0; i < 16; i++) { float e = expf(vals[i] - gmax); vals[i] = e; lsum += e; }
    s[t] = lsum; __syncthreads();
    for (int o = 512; o > 0; o >>= 1) { if (t < o) s[t] += s[t + o]; __syncthreads(); }
    float inv = 1.f / s[0];
    #pragma unroll
    for (int i = 0; i < 16; i++) pv[t + 1024 * i] = vals[i] * inv;
}

// K5: d[k] = sum_m p_v[m] * h_e_m[m][k]   grid 256 x 1024, atomic accumulate
__global__ void k_dvec(const float* __restrict__ hem, const float* __restrict__ pv,
                       float* __restrict__ dacc) {
    int k = threadIdx.x;
    int m0 = blockIdx.x * 64;
    __shared__ float ps[64];
    if (threadIdx.x < 64) ps[threadIdx.x] = pv[m0 + threadIdx.x];
    __syncthreads();
    float acc = 0.f;
    #pragma unroll 8
    for (int mm = 0; mm < 64; mm++)
        acc += ps[mm] * hem[(size_t)(m0 + mm) * H + k];
    atomicAdd(&dacc[k], acc);
}

// K6: z = sigmoid([h, d] . Wz_w + Wz_b)   1 block x 256
__global__ void k_z(const float* __restrict__ h, const float* __restrict__ dvec,
                    const float* __restrict__ Wz_w, const float* __restrict__ Wz_b,
                    float* __restrict__ out_z) {
    int t = threadIdx.x;
    float acc = 0.f;
    for (int i = t; i < H; i += 256) acc += h[i] * Wz_w[i] + dvec[i] * Wz_w[H + i];
    __shared__ float s[256];
    s[t] = acc; __syncthreads();
    for (int o = 128; o > 0; o >>= 1) { if (t < o) s[t] += s[t + o]; __syncthreads(); }
    if (t == 0) out_z[0] = sigmoidf_(s[0] + Wz_b[0]);
}

// K7: out_h[j] = tanh( sum_k h[k]*(W2[j][k] + W2[j][H+k]) + W2_b[j] )  grid 256 x 256
__global__ void k_fc2(const float* __restrict__ h, const float* __restrict__ W2_w,
                      const float* __restrict__ W2_b, float* __restrict__ oh) {
    int j = blockIdx.x * 4 + (threadIdx.x >> 6);
    int lane = threadIdx.x & 63;
    const float4* R = (const float4*)(W2_w + (size_t)j * 2 * H);
    const float4* H4 = (const float4*)h;
    float acc = 0.f;
    #pragma unroll
    for (int i = 0; i < 4; i++) {
        int idx = lane + 64 * i;
        float4 hv = H4[idx];
        float4 a = R[idx];
        float4 b = R[256 + idx];
        acc += hv.x * (a.x + b.x) + hv.y * (a.y + b.y) + hv.z * (a.z + b.z) + hv.w * (a.w + b.w);
    }
    acc = wave_reduce_sum(acc);
    if (lane == 0) oh[j] = tanhf(acc + W2_b[j]);
}

// K8: logits[r] = oh . W1_w[r] + W1_b[r]   grid ceil(V/4) x 256 (wave per row)
__global__ void k_fc1(const float* __restrict__ oh, const float* __restrict__ W1_w,
                      const float* __restrict__ W1_b, float* __restrict__ out) {
    int r = blockIdx.x * 4 + (threadIdx.x >> 6);
    if (r >= VOCAB) return;
    int lane = threadIdx.x & 63;
    const float4* A = (const float4*)(W1_w + (size_t)r * H);
    const float4* O4 = (const float4*)oh;
    float acc = 0.f;
    #pragma unroll
    for (int i = 0; i < 4; i++) {
        int idx = lane + 64 * i;
        float4 a = A[idx], b = O4[idx];
        acc += a.x * b.x + a.y * b.y + a.z * b.z + a.w * b.w;
    }
    acc = wave_reduce_sum(acc);
    if (lane == 0) out[r] = acc + W1_b[r];
}

extern "C" void kernel_launch(void* const* d_in, const int* in_sizes, int n_in,
                              void* d_out, int out_size, void* d_ws, size_t ws_size,
                              hipStream_t stream) {
    const int*   x      = (const int*)  d_in[0];
    // d_in[1] = entity_target: unused — new_mem[t] == h, scatter elides
    const float* emb    = (const float*)d_in[2];
    const float* W_ih   = (const float*)d_in[3];
    const float* W_hh   = (const float*)d_in[4];
    const float* b_ih   = (const float*)d_in[5];
    const float* b_hh   = (const float*)d_in[6];
    const float* h0     = (const float*)d_in[7];
    const float* c0     = (const float*)d_in[8];
    const float* hem    = (const float*)d_in[9];
    const float* Ws_w   = (const float*)d_in[10];
    // d_in[11] = Ws_b: uniform shift of all scores — cancels in softmax
    const float* Wz_w   = (const float*)d_in[12];
    const float* Wz_b   = (const float*)d_in[13];
    const float* W2_w   = (const float*)d_in[14];
    const float* W2_b   = (const float*)d_in[15];
    const float* W1_w   = (const float*)d_in[16];
    const float* W1_b   = (const float*)d_in[17];

    float* out  = (float*)d_out;              // logits [V]
    float* zout = out + VOCAB;                // z_i    [1]
    float* pv   = out + VOCAB + 1;            // p_v    [M]

    float* ws = (float*)d_ws;
    float* h  = ws;                 // 1024
    float* v  = ws + 1024;          // 1024 (atomic acc)
    float* sc = ws + 2048;          // 16384
    float* dv = ws + 18432;         // 1024 (atomic acc)
    float* oh = ws + 19456;         // 1024

    hipMemsetAsync(v,  0, H * sizeof(float), stream);
    hipMemsetAsync(dv, 0, H * sizeof(float), stream);

    k_lstm   <<<1024, 256, 0, stream>>>(x, emb, W_ih, W_hh, b_ih, b_hh, h0, c0, h);
    k_hWs    <<<64, 1024, 0, stream>>>(h, Ws_w, v);
    k_scores <<<M / 4, 256, 0, stream>>>(hem, v, sc);
    k_softmax<<<1, 1024, 0, stream>>>(sc, pv);
    k_dvec   <<<M / 64, 1024, 0, stream>>>(hem, pv, dv);
    k_z      <<<1, 256, 0, stream>>>(h, dv, Wz_w, Wz_b, zout);
    k_fc2    <<<H / 4, 256, 0, stream>>>(h, W2_w, W2_b, oh);
    k_fc1    <<<(VOCAB + 3) / 4, 256, 0, stream>>>(oh, W1_w, W1_b, out);
}

// Round 2
// 82.617 us; speedup vs baseline: 1.1536x; 1.1536x over previous
//
#include <hip/hip_runtime.h>
#include <hip/hip_bf16.h>

#define H 1024
#define E 1024
#define VOCAB 50257
#define M 16384

__device__ __forceinline__ float sigmoidf_(float x) { return 1.0f / (1.0f + expf(-x)); }

__device__ __forceinline__ float wave_sum(float v) {
    #pragma unroll
    for (int o = 32; o > 0; o >>= 1) v += __shfl_down(v, o);
    return v;
}

// K1: LSTM gates + h. Also zeroes the atomic accumulators (v, dv) and the
// combine counter for this call (runs before all consumers; graph-replay safe).
// grid 1024 (one block per hidden unit j), 256 thr (4 waves: gates i,f,g,o)
__global__ void k_lstm(const int* __restrict__ x, const float* __restrict__ emb,
                       const float* __restrict__ W_ih, const float* __restrict__ W_hh,
                       const float* __restrict__ b_ih, const float* __restrict__ b_hh,
                       const float* __restrict__ h0, const float* __restrict__ c0,
                       float* __restrict__ h_out, float* __restrict__ v_z,
                       float* __restrict__ dv_z, unsigned int* __restrict__ cnt) {
    int j = blockIdx.x;
    if (threadIdx.x == 0) {
        v_z[j] = 0.f;
        dv_z[j] = 0.f;
        if (j == 0) cnt[0] = 0u;
    }
    int w = threadIdx.x >> 6;
    int lane = threadIdx.x & 63;
    int r = w * H + j;                      // gate rows: i=j, f=H+j, g=2H+j, o=3H+j
    const float4* A  = (const float4*)(W_ih + (size_t)r * E);
    const float4* Bm = (const float4*)(W_hh + (size_t)r * H);
    const float4* xe = (const float4*)(emb + (size_t)x[0] * E);
    const float4* hp = (const float4*)h0;
    float acc = 0.f;
    #pragma unroll
    for (int i = 0; i < 4; i++) {
        int idx = lane + 64 * i;
        float4 a = A[idx],  xv = xe[idx];
        acc += a.x * xv.x + a.y * xv.y + a.z * xv.z + a.w * xv.w;
        float4 b = Bm[idx], hv = hp[idx];
        acc += b.x * hv.x + b.y * hv.y + b.z * hv.z + b.w * hv.w;
    }
    acc = wave_sum(acc);
    __shared__ float g[4];
    if (lane == 0) g[w] = acc + b_ih[r] + b_hh[r];
    __syncthreads();
    if (threadIdx.x == 0) {
        float c = sigmoidf_(g[1]) * c0[j] + sigmoidf_(g[0]) * tanhf(g[2]);
        h_out[j] = sigmoidf_(g[3]) * tanhf(c);
    }
}

// K2: v[k] = sum_j h[j] * Ws_w[j][k]   (Ws_b dropped: uniform softmax shift)
// grid 64 x 1024, atomic accumulate into v (zeroed by k_lstm)
__global__ void k_hWs(const float* __restrict__ h, const float* __restrict__ Ws_w,
                      float* __restrict__ v) {
    int k = threadIdx.x;
    int j0 = blockIdx.x * 16;
    __shared__ float hs[16];
    if (threadIdx.x < 16) hs[threadIdx.x] = h[j0 + threadIdx.x];
    __syncthreads();
    float acc = 0.f;
    #pragma unroll
    for (int jj = 0; jj < 16; jj++)
        acc += hs[jj] * Ws_w[(size_t)(j0 + jj) * H + k];
    atomicAdd(&v[k], acc);
}

// K3: fused one-HBM-pass attention partials. Block b owns 64 rows of h_e_m:
//   pass1: scores (wave-per-row dots) -> LDS + global sc
//   block-local max Mb, expsum Sb
//   pass2: partial d db[b][k] = sum_m exp(sc-Mb)*hem[m][k]  (rows re-read from L2)
// grid 256 x 1024
__global__ void k_attn(const float* __restrict__ hem, const float* __restrict__ v,
                       float* __restrict__ sc, float* __restrict__ db,
                       float* __restrict__ Mb, float* __restrict__ Sb) {
    __shared__ float s_sc[64];
    __shared__ float s_e[64];
    int b = blockIdx.x;
    int m0 = b * 64;
    int w = threadIdx.x >> 6, lane = threadIdx.x & 63;
    const float4* V4 = (const float4*)v;
    #pragma unroll
    for (int q = 0; q < 4; q++) {
        int mm = w * 4 + q;                 // 0..63
        const float4* A = (const float4*)(hem + (size_t)(m0 + mm) * H);
        float acc = 0.f;
        #pragma unroll
        for (int i = 0; i < 4; i++) {
            float4 a = A[lane + 64 * i], bb = V4[lane + 64 * i];
            acc += a.x * bb.x + a.y * bb.y + a.z * bb.z + a.w * bb.w;
        }
        acc = wave_sum(acc);
        if (lane == 0) { s_sc[mm] = acc; sc[m0 + mm] = acc; }
    }
    __syncthreads();
    if (w == 0) {                           // wave 0 reduces the 64 scores
        float xv = s_sc[lane];
        float mx = xv;
        #pragma unroll
        for (int o = 32; o > 0; o >>= 1) mx = fmaxf(mx, __shfl_down(mx, o));
        mx = __shfl(mx, 0);
        float e = expf(xv - mx);
        s_e[lane] = e;
        float ssum = wave_sum(e);
        if (lane == 0) { Mb[b] = mx; Sb[b] = ssum; }
    }
    __syncthreads();
    int k = threadIdx.x;
    float acc = 0.f;
    #pragma unroll 8
    for (int mm = 0; mm < 64; mm++)
        acc += s_e[mm] * hem[(size_t)(m0 + mm) * H + k];
    db[(size_t)b * H + k] = acc;
}

// K4: blocks [0,256): fc2  oh[j] = tanh(h . (W2[:, :H] + W2[:, H:]) + b)
//     blocks [256,272): softmax combine -> pv, dv (atomic), last block -> z
// grid 272 x 256
__global__ void k_comb_fc2(const float* __restrict__ h, const float* __restrict__ W2_w,
                           const float* __restrict__ W2_b, float* __restrict__ oh,
                           const float* __restrict__ sc, const float* __restrict__ db,
                           const float* __restrict__ Mb, const float* __restrict__ Sb,
                           float* __restrict__ pv, float* __restrict__ dv,
                           const float* __restrict__ Wz_w, const float* __restrict__ Wz_b,
                           float* __restrict__ zout, unsigned int* __restrict__ cnt) {
    if (blockIdx.x < 256) {                 // ---- fc2 ----
        int j = blockIdx.x * 4 + (threadIdx.x >> 6);
        int lane = threadIdx.x & 63;
        const float4* R  = (const float4*)(W2_w + (size_t)j * 2 * H);
        const float4* H4 = (const float4*)h;
        float acc = 0.f;
        #pragma unroll
        for (int i = 0; i < 4; i++) {
            int idx = lane + 64 * i;
            float4 hv = H4[idx];
            float4 a = R[idx];
            float4 b = R[256 + idx];
            acc += hv.x * (a.x + b.x) + hv.y * (a.y + b.y)
                 + hv.z * (a.z + b.z) + hv.w * (a.w + b.w);
        }
        acc = wave_sum(acc);
        if (lane == 0) oh[j] = tanhf(acc + W2_b[j]);
        return;
    }
    // ---- softmax combine ----
    int b2 = blockIdx.x - 256;              // 0..15
    int t = threadIdx.x;                    // 0..255
    __shared__ float s[256];
    __shared__ float s_w[16];
    __shared__ unsigned int s_old;
    float mval = Mb[t];
    s[t] = mval; __syncthreads();
    for (int o = 128; o > 0; o >>= 1) { if (t < o) s[t] = fmaxf(s[t], s[t + o]); __syncthreads(); }
    float gmax = s[0]; __syncthreads();
    s[t] = Sb[t] * expf(mval - gmax); __syncthreads();
    for (int o = 128; o > 0; o >>= 1) { if (t < o) s[t] += s[t + o]; __syncthreads(); }
    float inv = 1.f / s[0]; __syncthreads();
    int base = b2 * 1024;
    #pragma unroll
    for (int q = 0; q < 4; q++) {
        int i = base + t + 256 * q;
        pv[i] = expf(sc[i] - gmax) * inv;
    }
    if (t < 16) s_w[t] = expf(Mb[b2 * 16 + t] - gmax) * inv;
    __syncthreads();
    float a0 = 0.f, a1 = 0.f, a2 = 0.f, a3 = 0.f;
    #pragma unroll
    for (int rr = 0; rr < 16; rr++) {
        const float* row = db + (size_t)(b2 * 16 + rr) * H;
        float wr = s_w[rr];
        a0 += wr * row[t];       a1 += wr * row[t + 256];
        a2 += wr * row[t + 512]; a3 += wr * row[t + 768];
    }
    atomicAdd(&dv[t], a0);       atomicAdd(&dv[t + 256], a1);
    atomicAdd(&dv[t + 512], a2); atomicAdd(&dv[t + 768], a3);
    __threadfence();
    if (t == 0) s_old = atomicAdd(cnt, 1u);
    __syncthreads();
    if (s_old == 15u) {                     // last combine block computes z
        __threadfence();
        float acc = 0.f;
        for (int i = t; i < H; i += 256) acc += h[i] * Wz_w[i] + dv[i] * Wz_w[H + i];
        s[t] = acc; __syncthreads();
        for (int o = 128; o > 0; o >>= 1) { if (t < o) s[t] += s[t + o]; __syncthreads(); }
        if (t == 0) zout[0] = sigmoidf_(s[0] + Wz_b[0]);
    }
}

// K5: logits[r] = oh . W1_w[r] + W1_b[r]   grid ceil(V/4) x 256 (wave per row)
__global__ void k_fc1(const float* __restrict__ oh, const float* __restrict__ W1_w,
                      const float* __restrict__ W1_b, float* __restrict__ out) {
    int r = blockIdx.x * 4 + (threadIdx.x >> 6);
    if (r >= VOCAB) return;
    int lane = threadIdx.x & 63;
    const float4* A  = (const float4*)(W1_w + (size_t)r * H);
    const float4* O4 = (const float4*)oh;
    float acc = 0.f;
    #pragma unroll
    for (int i = 0; i < 4; i++) {
        int idx = lane + 64 * i;
        float4 a = A[idx], b = O4[idx];
        acc += a.x * b.x + a.y * b.y + a.z * b.z + a.w * b.w;
    }
    acc = wave_sum(acc);
    if (lane == 0) out[r] = acc + W1_b[r];
}

extern "C" void kernel_launch(void* const* d_in, const int* in_sizes, int n_in,
                              void* d_out, int out_size, void* d_ws, size_t ws_size,
                              hipStream_t stream) {
    const int*   x      = (const int*)  d_in[0];
    // d_in[1] entity_target: unused — new_mem[t] == h, scatter elides
    const float* emb    = (const float*)d_in[2];
    const float* W_ih   = (const float*)d_in[3];
    const float* W_hh   = (const float*)d_in[4];
    const float* b_ih   = (const float*)d_in[5];
    const float* b_hh   = (const float*)d_in[6];
    const float* h0     = (const float*)d_in[7];
    const float* c0     = (const float*)d_in[8];
    const float* hem    = (const float*)d_in[9];
    const float* Ws_w   = (const float*)d_in[10];
    // d_in[11] Ws_b: uniform shift of all scores — cancels in softmax
    const float* Wz_w   = (const float*)d_in[12];
    const float* Wz_b   = (const float*)d_in[13];
    const float* W2_w   = (const float*)d_in[14];
    const float* W2_b   = (const float*)d_in[15];
    const float* W1_w   = (const float*)d_in[16];
    const float* W1_b   = (const float*)d_in[17];

    float* out  = (float*)d_out;              // logits [V]
    float* zout = out + VOCAB;                // z_i    [1]
    float* pv   = out + VOCAB + 1;            // p_v    [M]

    float* ws = (float*)d_ws;
    float* h   = ws;                  // 1024
    float* v   = ws + 1024;           // 1024 (atomic acc, zeroed in k_lstm)
    float* sc  = ws + 2048;           // 16384
    float* dv  = ws + 18432;          // 1024 (atomic acc, zeroed in k_lstm)
    float* oh  = ws + 19456;          // 1024
    float* Mb  = ws + 20480;          // 256
    float* Sb  = ws + 20736;          // 256
    unsigned int* cnt = (unsigned int*)(ws + 20992);   // 1 (zeroed in k_lstm)
    float* db  = ws + 21504;          // 256*1024 = 1 MB partial d vectors

    k_lstm    <<<1024, 256, 0, stream>>>(x, emb, W_ih, W_hh, b_ih, b_hh, h0, c0,
                                         h, v, dv, cnt);
    k_hWs     <<<64, 1024, 0, stream>>>(h, Ws_w, v);
    k_attn    <<<256, 1024, 0, stream>>>(hem, v, sc, db, Mb, Sb);
    k_comb_fc2<<<272, 256, 0, stream>>>(h, W2_w, W2_b, oh, sc, db, Mb, Sb,
                                        pv, dv, Wz_w, Wz_b, zout, cnt);
    k_fc1     <<<(VOCAB + 3) / 4, 256, 0, stream>>>(oh, W1_w, W1_b, out);
}